// Round 7
// baseline (110.317 us; speedup 1.0000x reference)
//
#include <hip/hip_runtime.h>
#include <stdint.h>

#define B_ 64
#define S_ 512
#define EMB_ 256
#define NIN_ 7
#define NOUT_ 4
#define HID_ 512
#define VOCAB_ 1000
#define VP_ 1024          // vocab padded to 1024 rows
#define NG_ 2048          // W4 virtual cols: [fwd 1024 | bwd 1024]

typedef __bf16 bf16x8 __attribute__((ext_vector_type(8)));
typedef float floatx4 __attribute__((ext_vector_type(4)));
typedef unsigned short u16x8 __attribute__((ext_vector_type(8)));
typedef unsigned long long ull;

__device__ __forceinline__ unsigned short f2bf(float f) {
    unsigned u = __float_as_uint(f);
    u += 0x7FFFu + ((u >> 16) & 1u);   // RNE
    return (unsigned short)(u >> 16);
}
__device__ __forceinline__ float bf2f(unsigned short h) {
    return __uint_as_float(((unsigned)h) << 16);
}
__device__ __forceinline__ float rcp_(float x) { return __builtin_amdgcn_rcpf(x); }
__device__ __forceinline__ float exp2_(float x) {
    float r; asm("v_exp_f32 %0, %1" : "=v"(r) : "v"(x)); return r;
}
#define L2E_ 1.4426950408889634f
__device__ __forceinline__ float sigmoidf_(float x) {
    return rcp_(1.0f + exp2_(x * (-L2E_)));
}
__device__ __forceinline__ float tanhf_(float x) {
    float ax = fabsf(x);
    float e = exp2_(ax * (-2.0f * L2E_));
    float t = (1.0f - e) * rcp_(1.0f + e);
    return copysignf(t, x);
}

// Session ledger (R7):
//  - R1..R5 ~110 across 4 structures; R6 (scan full-reg preload) 102.4:
//    scan gather latency was real (-8.2us, prediction matched).
//    fill ~42us harness-fixed; persistent grid barriers net-negative (R2/R3).
//  - R7: prep dispatch ELIMINATED. gemm builds A-frags directly from emb
//    (2x float4 + f2bf, bit-identical) and B-frags via in-block LDS transpose
//    of the W slice (prep's staging loop inlined, reg-double-buffered so
//    next k-tile's loads overlap MFMA). Bias inlined in epilogue (same fmaf
//    order). W4/bcnt built by 8 spare blocks of the same dispatch (only read
//    by the NEXT dispatch -> no intra-dispatch dependency). 3 -> 2 dispatches.
//  - If this is null (>=101), dispatch-structure lever is exhausted ->
//    declare fill+slop floor.

// ---------------- K1: gemmF — fused prep+gemm -------------------------------
// grid 80 x 256: [0,64) fwd 128x128 tiles | [64,72) bwd 64x128 | [72,80) W4
__global__ __launch_bounds__(256) void gemmF(
    const float* __restrict__ X, const float* __restrict__ emb,
    const float* __restrict__ bn, const float* __restrict__ Wf,
    const float* __restrict__ bfv, const float* __restrict__ Wb,
    const float* __restrict__ bb,
    unsigned short* __restrict__ G1, unsigned short* __restrict__ Gb,
    float* __restrict__ W4, unsigned* __restrict__ bcnt) {
    int bid = blockIdx.x;
    int tid = threadIdx.x;

    if (bid >= 72) {                        // ---- W4 (4 x 2048) + bcnt -------
        int v = (bid - 72) * 256 + tid;
        int part = v >> 10;
        int m = v & 1023;
        int c = (m & 1) ? (512 + (m >> 1)) : (m >> 1);
        const float* W = part ? Wb : Wf;
#pragma unroll
        for (int q = 0; q < NOUT_; ++q)
            W4[(size_t)q * NG_ + v] = W[(size_t)(256 + q) * 1536 + c];
        if (bid == 72 && tid < 64) bcnt[tid] = 0;
        return;
    }

    __shared__ float raw[32][132];          // one k-tile of W, transposed view
    __shared__ int evs[64];
    const bool fwd = (bid < 64);
    int mtile = fwd ? (bid & 7) : 0;
    int ntile = fwd ? (bid >> 3) : (bid - 64);
    const float* Wsrc = fwd ? Wf : Wb;
    const float* bsrc = fwd ? bfv : bb;
    int j0 = ntile * 64;
    int lane = tid & 63, wave = tid >> 6;
    int rl = lane & 15, kq = lane >> 4;     // kq = k-chunk 0..3
    int sr = tid >> 3, si = tid & 7;        // staging row / col-octet
    int wm = wave & 1, wn = wave >> 1;

    float bnr[NOUT_];
#pragma unroll
    for (int q = 0; q < NOUT_; ++q) bnr[q] = bn[q];

    if (!fwd && tid < 64)
        evs[tid] = (int)X[((size_t)tid * S_ + (S_ - 1)) * 8];

    floatx4 acc[4][4];
#pragma unroll
    for (int mi = 0; mi < 4; ++mi)
#pragma unroll
        for (int ni = 0; ni < 4; ++ni) acc[mi][ni] = (floatx4){0.f, 0.f, 0.f, 0.f};

    // reg-staged W double buffer: thread owns k-row sr, col-octet si
    const float* src0 = Wsrc + (size_t)sr * 1536;
    float4 sa0 = *(const float4*)(src0 + j0 + si * 8);
    float4 sa1 = *(const float4*)(src0 + j0 + si * 8 + 4);
    float4 sb0 = *(const float4*)(src0 + 512 + j0 + si * 8);
    float4 sb1 = *(const float4*)(src0 + 512 + j0 + si * 8 + 4);

#pragma unroll
    for (int kt = 0; kt < 8; ++kt) {
        if (kt) __syncthreads();            // prior k-tile's raw reads done
        *(float4*)&raw[sr][si * 8]          = sa0;
        *(float4*)&raw[sr][si * 8 + 4]      = sa1;
        *(float4*)&raw[sr][64 + si * 8]     = sb0;
        *(float4*)&raw[sr][64 + si * 8 + 4] = sb1;
        __syncthreads();
        if (kt < 7) {                       // prefetch next k-tile (covers MFMA)
            const float* srcn = Wsrc + (size_t)(32 * (kt + 1) + sr) * 1536;
            sa0 = *(const float4*)(srcn + j0 + si * 8);
            sa1 = *(const float4*)(srcn + j0 + si * 8 + 4);
            sb0 = *(const float4*)(srcn + 512 + j0 + si * 8);
            sb1 = *(const float4*)(srcn + 512 + j0 + si * 8 + 4);
        }
        int k0 = kt * 32 + kq * 8;

        if (fwd) {
            bf16x8 bf[4];
#pragma unroll
            for (int ni = 0; ni < 4; ++ni) {
                int vc = wn * 64 + ni * 16 + rl;            // vcol within tile
                int cl = (vc >> 1) + 64 * (vc & 1);
                unsigned short pk[8];
#pragma unroll
                for (int q = 0; q < 8; ++q) pk[q] = f2bf(raw[kq * 8 + q][cl]);
                bf[ni] = *(const bf16x8*)pk;
            }
#pragma unroll
            for (int mi = 0; mi < 4; ++mi) {
                int row = mtile * 128 + wm * 64 + mi * 16 + rl;
                unsigned short pa[8];
                if (row < VOCAB_) {
                    float4 a = *(const float4*)(emb + (size_t)row * EMB_ + k0);
                    float4 b = *(const float4*)(emb + (size_t)row * EMB_ + k0 + 4);
                    pa[0]=f2bf(a.x); pa[1]=f2bf(a.y); pa[2]=f2bf(a.z); pa[3]=f2bf(a.w);
                    pa[4]=f2bf(b.x); pa[5]=f2bf(b.y); pa[6]=f2bf(b.z); pa[7]=f2bf(b.w);
                } else {
#pragma unroll
                    for (int q = 0; q < 8; ++q) pa[q] = 0;
                }
                bf16x8 af = *(const bf16x8*)pa;
#pragma unroll
                for (int ni = 0; ni < 4; ++ni)
                    acc[mi][ni] = __builtin_amdgcn_mfma_f32_16x16x32_bf16(af, bf[ni], acc[mi][ni], 0, 0, 0);
            }
        } else {
            bf16x8 bf[2];
#pragma unroll
            for (int ni = 0; ni < 2; ++ni) {
                int vc = wave * 32 + ni * 16 + rl;
                int cl = (vc >> 1) + 64 * (vc & 1);
                unsigned short pk[8];
#pragma unroll
                for (int q = 0; q < 8; ++q) pk[q] = f2bf(raw[kq * 8 + q][cl]);
                bf[ni] = *(const bf16x8*)pk;
            }
#pragma unroll
            for (int mi = 0; mi < 4; ++mi) {
                int row = evs[16 * mi + rl];
                float4 a = *(const float4*)(emb + (size_t)row * EMB_ + k0);
                float4 b = *(const float4*)(emb + (size_t)row * EMB_ + k0 + 4);
                unsigned short pa[8];
                pa[0]=f2bf(a.x); pa[1]=f2bf(a.y); pa[2]=f2bf(a.z); pa[3]=f2bf(a.w);
                pa[4]=f2bf(b.x); pa[5]=f2bf(b.y); pa[6]=f2bf(b.z); pa[7]=f2bf(b.w);
                bf16x8 af = *(const bf16x8*)pa;
#pragma unroll
                for (int ni = 0; ni < 2; ++ni)
                    acc[mi][ni] = __builtin_amdgcn_mfma_f32_16x16x32_bf16(af, bf[ni], acc[mi][ni], 0, 0, 0);
            }
        }
    }

    // epilogue — bias inlined (same fmaf order as old prep => bit-identical)
    // C/D: col = lane&15, row = (lane>>4)*4 + reg  [m89/m91]
    if (fwd) {
#pragma unroll
        for (int ni = 0; ni < 4; ++ni) {
            int n = ntile * 128 + 64 * wn + 16 * ni + rl;   // fwd vcol 0..1023
            int c = (n & 1) ? (512 + (n >> 1)) : (n >> 1);
            float bv = bsrc[c];
#pragma unroll
            for (int q = 0; q < NOUT_; ++q)
                bv = fmaf(bnr[q], Wsrc[(size_t)(256 + q) * 1536 + c], bv);
#pragma unroll
            for (int mi = 0; mi < 4; ++mi) {
                int rb = mtile * 128 + 64 * wm + 16 * mi + (lane >> 4) * 4;
#pragma unroll
                for (int v = 0; v < 4; ++v)
                    G1[(size_t)(rb + v) * 1024 + n] = f2bf(acc[mi][ni][v] + bv);
            }
        }
    } else {
#pragma unroll
        for (int ni = 0; ni < 2; ++ni) {
            int n = ntile * 128 + 32 * wave + 16 * ni + rl;
            int c = (n & 1) ? (512 + (n >> 1)) : (n >> 1);
            float bv = bsrc[c];
#pragma unroll
            for (int q = 0; q < NOUT_; ++q)
                bv = fmaf(bnr[q], Wsrc[(size_t)(256 + q) * 1536 + c], bv);
#pragma unroll
            for (int mi = 0; mi < 4; ++mi) {
                int rb = 16 * mi + (lane >> 4) * 4;         // batch row
#pragma unroll
                for (int v = 0; v < 4; ++v)
                    Gb[(size_t)(rb + v) * 1024 + n] = f2bf(acc[mi][ni][v] + bv);
            }
        }
    }
}

// ---------------- K2: gather-scan (full register preload) + fused final -----
__global__ __launch_bounds__(512, 4) void scanF(
    const float* __restrict__ X, const unsigned short* __restrict__ G1,
    const unsigned short* __restrict__ Gb, const float* __restrict__ W4,
    const float* __restrict__ Wn, const float* __restrict__ Wo,
    const float* __restrict__ bo, float* __restrict__ PQ,
    unsigned* __restrict__ bcnt, float* __restrict__ out) {
    __shared__ float LX[512];               // 64 steps x 8 floats
    __shared__ float LN[64][4];             // per-token n4 = num @ Wn
    __shared__ int   LO[64];                // per-token G1 row byte-offset
    __shared__ unsigned lastf;
    __shared__ float red[8];
    int bid = blockIdx.x;
    int b = bid >> 3, chunk = bid & 7;
    int s0 = chunk * 64;
    int j = threadIdx.x;                    // chain 0..511

    // hoisted: w4p loads are independent of LX (in flight across the barrier)
    float2 w4p[NOUT_];
#pragma unroll
    for (int q = 0; q < NOUT_; ++q)
        w4p[q] = *(const float2*)(W4 + (size_t)q * NG_ + 2 * j);

    if (j < 128) {
        const float* xb = X + ((size_t)b * S_ + s0) * 8;
        *(float4*)&LX[4 * j] = *(const float4*)(xb + 4 * j);
    }
    __syncthreads();

    if (j < 64) LO[j] = (int)LX[j * 8] * 2048;   // G1 row = 1024 shorts = 2KB
    if (j < 256) {                          // token t = j>>2, output q = j&3
        int t = j >> 2, q = j & 3;
        float s = 0.f;
#pragma unroll
        for (int i = 0; i < NIN_; ++i) s = fmaf(LX[t * 8 + 1 + i], Wn[i * NOUT_ + q], s);
        LN[t][q] = s;
    }
    __syncthreads();

    // ---- full preload: 64 independent 4B gathers, one burst, one drain ----
    const char* Gbase = (const char*)G1 + 4 * j;
    unsigned gp[64];
#pragma unroll
    for (int m = 0; m < 16; ++m) {
        int4 lo = *(const int4*)&LO[4 * m];
        gp[4 * m + 0] = *(const unsigned*)(Gbase + lo.x);
        gp[4 * m + 1] = *(const unsigned*)(Gbase + lo.y);
        gp[4 * m + 2] = *(const unsigned*)(Gbase + lo.z);
        gp[4 * m + 3] = *(const unsigned*)(Gbase + lo.w);
    }

    float P = 1.f, Q = 0.f;
#pragma unroll
    for (int s = 0; s < 64; ++s) {
        unsigned gpc = gp[s];               // static index (full unroll)
        float gz = bf2f((unsigned short)(gpc & 0xffffu));
        float gf = bf2f((unsigned short)(gpc >> 16));
        float4 n4 = *(const float4*)(&LN[s][0]);    // uniform b128 broadcast
        gz = fmaf(n4.x, w4p[0].x, gz);
        gz = fmaf(n4.y, w4p[1].x, gz);
        gz = fmaf(n4.z, w4p[2].x, gz);
        gz = fmaf(n4.w, w4p[3].x, gz);
        gf = fmaf(n4.x, w4p[0].y, gf);
        gf = fmaf(n4.y, w4p[1].y, gf);
        gf = fmaf(n4.z, w4p[2].y, gf);
        gf = fmaf(n4.w, w4p[3].y, gf);
        float z = tanhf_(gz);
        float f = sigmoidf_(gf);
        Q = fmaf(f, Q - z, z);              // f*Q + (1-f)*z
        P *= f;
    }
    {   // write-through 8B store to the coherent point (R3-proven)
        union { float2 f; ull q; } pv;
        pv.f = make_float2(P, Q);
        __hip_atomic_store((ull*)PQ + (size_t)bid * 512 + j, pv.q,
                           __ATOMIC_RELAXED, __HIP_MEMORY_SCOPE_AGENT);
    }

    // -------- per-batch trigger: 8th-arriving chunk block runs the fold -----
    __syncthreads();                        // drains the PQ stores (vmcnt0)
    if (j == 0) {
        unsigned old = __hip_atomic_fetch_add(bcnt + b, 1u, __ATOMIC_RELAXED,
                                              __HIP_MEMORY_SCOPE_AGENT);
        lastf = (old == 7u);
    }
    __syncthreads();

    if (lastf) {                            // ---- final fold for batch b ----
        float h = 0.f;
#pragma unroll
        for (int c = 0; c < 8; ++c) {
            union { float2 f; ull q; } pv;
            pv.q = __hip_atomic_load((const ull*)PQ + ((size_t)b * 8 + c) * 512 + j,
                                     __ATOMIC_RELAXED, __HIP_MEMORY_SCOPE_AGENT);
            h = fmaf(pv.f.x, h, pv.f.y);
        }

        const float* xr = X + ((size_t)b * S_ + (S_ - 1)) * 8;
        float n4[NOUT_];
#pragma unroll
        for (int q = 0; q < NOUT_; ++q) {
            float s = 0.f;
#pragma unroll
            for (int i = 0; i < NIN_; ++i) s = fmaf(xr[1 + i], Wn[i * NOUT_ + q], s);
            n4[q] = s;
        }
        unsigned gpc = *(const unsigned*)(Gb + (size_t)b * 1024 + 2 * j);  // coalesced
        float gz = bf2f((unsigned short)(gpc & 0xffffu));
        float gf = bf2f((unsigned short)(gpc >> 16));
#pragma unroll
        for (int q = 0; q < NOUT_; ++q) {
            float2 w = *(const float2*)(W4 + (size_t)q * NG_ + 1024 + 2 * j);
            gz = fmaf(n4[q], w.x, gz);
            gf = fmaf(n4[q], w.y, gf);
        }
        float hb = (1.f - sigmoidf_(gf)) * tanhf_(gz);

        float partial = fmaf(h, Wo[j], hb * Wo[512 + j]);
#pragma unroll
        for (int off = 32; off > 0; off >>= 1)
            partial += __shfl_down(partial, off);
        if ((j & 63) == 0) red[j >> 6] = partial;
        __syncthreads();
        if (j == 0) {
            float s = bo[0];
#pragma unroll
            for (int w = 0; w < 8; ++w) s += red[w];
            out[b] = s;
        }
    }
}

extern "C" void kernel_launch(void* const* d_in, const int* in_sizes, int n_in,
                              void* d_out, int out_size, void* d_ws, size_t ws_size,
                              hipStream_t stream) {
    const float* X   = (const float*)d_in[0];
    const float* emb = (const float*)d_in[1];
    const float* Wn  = (const float*)d_in[2];
    const float* bn  = (const float*)d_in[3];
    const float* Wf  = (const float*)d_in[4];
    const float* bfv = (const float*)d_in[5];
    const float* Wb  = (const float*)d_in[6];
    const float* bb  = (const float*)d_in[7];
    const float* Wo  = (const float*)d_in[8];
    const float* bo  = (const float*)d_in[9];
    float* out = (float*)d_out;

    size_t off_G1 = 0;
    size_t off_Gb = off_G1 + (size_t)VP_ * 1024 * 2;          // 2 MB
    size_t off_W4 = off_Gb + (size_t)B_ * 1024 * 2;           // +128 KB
    size_t off_PQ = off_W4 + (size_t)NOUT_ * NG_ * 4;         // +32 KB
    size_t off_bc = off_PQ + (size_t)B_ * 8 * 512 * 2 * sizeof(float);  // +2 MB
    size_t need   = off_bc + 64 * sizeof(unsigned);
    if (ws_size < need) return;

    unsigned short* G1   = (unsigned short*)((char*)d_ws + off_G1);
    unsigned short* Gb   = (unsigned short*)((char*)d_ws + off_Gb);
    float*          W4   = (float*)((char*)d_ws + off_W4);
    float*          PQ   = (float*)((char*)d_ws + off_PQ);
    unsigned*       bcnt = (unsigned*)((char*)d_ws + off_bc);

    gemmF<<<80, 256, 0, stream>>>(X, emb, bn, Wf, bfv, Wb, bb, G1, Gb, W4, bcnt);
    scanF<<<512, 512, 0, stream>>>(X, G1, Gb, W4, Wn, Wo, bo, PQ, bcnt, out);
}

// Round 8
// 102.934 us; speedup vs baseline: 1.0717x; 1.0717x over previous
//
#include <hip/hip_runtime.h>
#include <stdint.h>

#define B_ 64
#define S_ 512
#define EMB_ 256
#define NIN_ 7
#define NOUT_ 4
#define HID_ 512
#define VOCAB_ 1000
#define VP_ 1024          // vocab padded to 1024 rows
#define NG_ 2048          // W4/bvec virtual cols: [fwd 1024 | bwd 1024]

typedef __bf16 bf16x8 __attribute__((ext_vector_type(8)));
typedef float floatx4 __attribute__((ext_vector_type(4)));
typedef unsigned short u16x8 __attribute__((ext_vector_type(8)));
typedef unsigned long long ull;

__device__ __forceinline__ unsigned short f2bf(float f) {
    unsigned u = __float_as_uint(f);
    u += 0x7FFFu + ((u >> 16) & 1u);   // RNE
    return (unsigned short)(u >> 16);
}
__device__ __forceinline__ float bf2f(unsigned short h) {
    return __uint_as_float(((unsigned)h) << 16);
}
__device__ __forceinline__ float rcp_(float x) { return __builtin_amdgcn_rcpf(x); }
__device__ __forceinline__ float exp2_(float x) {
    float r; asm("v_exp_f32 %0, %1" : "=v"(r) : "v"(x)); return r;
}
#define L2E_ 1.4426950408889634f
__device__ __forceinline__ float sigmoidf_(float x) {
    return rcp_(1.0f + exp2_(x * (-L2E_)));
}
__device__ __forceinline__ float tanhf_(float x) {
    float ax = fabsf(x);
    float e = exp2_(ax * (-2.0f * L2E_));
    float t = (1.0f - e) * rcp_(1.0f + e);
    return copysignf(t, x);
}

// Session ledger (R8):
//  - R6 = 102.4 (best): prep tables + gemm + scan-with-full-reg-preload.
//  - R7 = 110.3 REGRESSION: prep-into-gemm fusion. gemmF 45us wall at
//    VALUBusy 1.8%, 491K LDS bank conflicts: per-lane scalar transpose reads
//    re-done x8 blocks, 80-block grid, 2 barriers/kt with nothing resident
//    to cover. Lesson: transpose ONCE in prep (coalesced), read b128 in gemm.
//    Do not re-fuse.
//  - R2/R3: persistent grid barriers net-negative. R6 scan preload: real -8us.
//  - R8 = R6 revert + gemm fwd re-tiled 128x64 (72 -> 136 blocks, same MFMA
//    count, 2x CU spread) + scanF prologue tweaks from R7 (w4p hoist, float4
//    LX). If >=102: controllable pipeline exhausted -> declare floor.

// ---------------- K1: prep: Aemb frags, WT frags, W4/bvec, bcnt=0 -----------
// grid 200 x 256: [0,64) Aemb | [64,192) WT jobs (stripe,kt) | [192,200) W4
__global__ __launch_bounds__(256) void prep(
    const float* __restrict__ emb, const float* __restrict__ bn,
    const float* __restrict__ Wf, const float* __restrict__ bfv,
    const float* __restrict__ Wb, const float* __restrict__ bb,
    unsigned short* __restrict__ Aemb, unsigned short* __restrict__ WT,
    float* __restrict__ W4, float* __restrict__ bvec,
    unsigned* __restrict__ bcnt) {
    int bid = blockIdx.x;
    int tid = threadIdx.x;

    if (bid < 64) {                         // ---- Aemb: rows 16*bid..+15
        int g = bid;
#pragma unroll
        for (int half = 0; half < 2; ++half) {
            int t = tid + 256 * half;
            int r15 = t & 15;
            int kchunk = (t >> 4) & 3;
            int kt = t >> 6;                // 0..7
            int row = g * 16 + r15;
            int k0 = kt * 32 + kchunk * 8;
            unsigned short p[8];
            if (row < VOCAB_) {
                float4 a = *(const float4*)(emb + (size_t)row * EMB_ + k0);
                float4 b = *(const float4*)(emb + (size_t)row * EMB_ + k0 + 4);
                p[0]=f2bf(a.x); p[1]=f2bf(a.y); p[2]=f2bf(a.z); p[3]=f2bf(a.w);
                p[4]=f2bf(b.x); p[5]=f2bf(b.y); p[6]=f2bf(b.z); p[7]=f2bf(b.w);
            } else {
#pragma unroll
                for (int q = 0; q < 8; ++q) p[q] = 0;
            }
            size_t chunk = ((size_t)(g >> 3) * 8 + kt) * 8 + (g & 7);
            *(u16x8*)(Aemb + chunk * 512 + (16 * kchunk + r15) * 8) =
                *(const u16x8*)p;
        }
    } else if (bid < 192) {                 // ---- WT: one (stripe idx, kt) job
        __shared__ float raw[32][132];      // 32 k-rows x 128 cols (pad 132)
        int job = bid - 64;                 // 0..127
        int idx = job >> 3;                 // 0..15
        int kt  = job & 7;                  // 0..7
        int p = idx >> 3;                   // part: 0 fwd, 1 bwd
        int gq = idx & 7;                   // col-stripe: j0 = gq*64
        const float* W = p ? Wb : Wf;
        int j0 = gq * 64;
        int r = tid >> 3;                   // 0..31 (k-row within tile)
        int i = tid & 7;                    // 0..7  (8 threads per row)
        int k0 = kt * 32;

        const float* src = W + (size_t)(k0 + r) * 1536;
        // stripe A: z-gate cols j0..j0+63; stripe B: f-gate cols 512+j0..+63
        float4 a0 = *(const float4*)(src + j0 + i * 8);
        float4 a1 = *(const float4*)(src + j0 + i * 8 + 4);
        float4 b0 = *(const float4*)(src + 512 + j0 + i * 8);
        float4 b1 = *(const float4*)(src + 512 + j0 + i * 8 + 4);
        *(float4*)&raw[r][i * 8]          = a0;
        *(float4*)&raw[r][i * 8 + 4]      = a1;
        *(float4*)&raw[r][64 + i * 8]     = b0;
        *(float4*)&raw[r][64 + i * 8 + 4] = b1;
        __syncthreads();
#pragma unroll
        for (int h = 0; h < 2; ++h) {
            int e = tid + 256 * h;          // 0..511 fragment entries
            int gl = e >> 6;                // 0..7 local group
            int rest = e & 63;
            int kchunk = rest >> 4;
            int v15 = rest & 15;
            int joff = gl * 8 + (v15 >> 1);
            int cl = joff + 64 * (v15 & 1);
            unsigned short pk[8];
#pragma unroll
            for (int q = 0; q < 8; ++q) pk[q] = f2bf(raw[kchunk * 8 + q][cl]);
            int g = p * 64 + gq * 8 + gl;
            size_t chunk = ((size_t)(g >> 3) * 8 + kt) * 8 + (g & 7);
            *(u16x8*)(WT + chunk * 512 + (16 * kchunk + v15) * 8) =
                *(const u16x8*)pk;
        }
    } else {                                // ---- W4 (4 x 2048) + bvec (2048)
        int v = (bid - 192) * 256 + tid;
        int part = v >> 10;
        int m = v & 1023;
        int j = m >> 1;
        int c = (m & 1) ? (512 + j) : j;
        const float* W = part ? Wb : Wf;
        float bv = part ? bb[c] : bfv[c];
#pragma unroll
        for (int q = 0; q < NOUT_; ++q) {
            float w = W[(size_t)(256 + q) * 1536 + c];
            W4[(size_t)q * NG_ + v] = w;
            bv = fmaf(bn[q], w, bv);
        }
        bvec[v] = bv;
        if (bid == 192 && tid < 64) bcnt[tid] = 0;   // scan's batch counters
    }
}

// ---------------- K2: gemm --------------------------------------------------
// blocks [0,128): fwd G1 = Aemb @ WT_fwd + b, 128x64 tiles (8 mtiles x 16 nt)
// blocks [128,136): bwd Gb = Aemb[ev_last] @ WT_bwd + b (64 x 128 tiles)
__global__ __launch_bounds__(256) void gemmG(
    const float* __restrict__ X,
    const unsigned short* __restrict__ Aemb, const unsigned short* __restrict__ WT,
    const float* __restrict__ bvec,
    unsigned short* __restrict__ G1, unsigned short* __restrict__ Gb) {
    int bid = blockIdx.x;
    int tid = threadIdx.x;
    int lane = tid & 63, wave = tid >> 6;
    int rl = lane & 15;

    if (bid < 128) {                        // ============== fwd 128x64 tile
        int mtile = bid & 7;                // 128-row stripe
        int ntile = bid >> 3;               // 0..15: 64-col stripe
        int wm = wave & 1, wn = wave >> 1;  // 64-row half / 32-col half

        const unsigned short* pa = Aemb + ((size_t)mtile * 64 + 4 * wm) * 512 + lane * 8;
        // B fragment group g = ntile*4 + wn*2 + ni; chunked layout:
        // off(g,kt) = (g>>3)*32768 + kt*4096 + (g&7)*512
        int goff[2];
#pragma unroll
        for (int ni = 0; ni < 2; ++ni) {
            int g = ntile * 4 + wn * 2 + ni;
            goff[ni] = (g >> 3) * 32768 + (g & 7) * 512;
        }

        floatx4 acc[4][2];
#pragma unroll
        for (int mi = 0; mi < 4; ++mi)
#pragma unroll
            for (int ni = 0; ni < 2; ++ni) acc[mi][ni] = (floatx4){0.f, 0.f, 0.f, 0.f};

        bf16x8 afc[4], bfc[2], afn[4], bfn[2];
#pragma unroll
        for (int mi = 0; mi < 4; ++mi) afc[mi] = *(const bf16x8*)(pa + mi * 512);
#pragma unroll
        for (int ni = 0; ni < 2; ++ni) bfc[ni] = *(const bf16x8*)(WT + goff[ni] + lane * 8);

#pragma unroll
        for (int kt = 0; kt < 8; ++kt) {
            if (kt < 7) {
#pragma unroll
                for (int mi = 0; mi < 4; ++mi)
                    afn[mi] = *(const bf16x8*)(pa + (size_t)(kt + 1) * 4096 + mi * 512);
#pragma unroll
                for (int ni = 0; ni < 2; ++ni)
                    bfn[ni] = *(const bf16x8*)(WT + goff[ni] + (kt + 1) * 4096 + lane * 8);
            }
#pragma unroll
            for (int mi = 0; mi < 4; ++mi)
#pragma unroll
                for (int ni = 0; ni < 2; ++ni)
                    acc[mi][ni] = __builtin_amdgcn_mfma_f32_16x16x32_bf16(afc[mi], bfc[ni], acc[mi][ni], 0, 0, 0);
            if (kt < 7) {
#pragma unroll
                for (int mi = 0; mi < 4; ++mi) afc[mi] = afn[mi];
#pragma unroll
                for (int ni = 0; ni < 2; ++ni) bfc[ni] = bfn[ni];
            }
        }

        // C/D: col = lane&15, row = (lane>>4)*4 + reg  [m89/m91]
#pragma unroll
        for (int ni = 0; ni < 2; ++ni) {
            int n = ntile * 64 + 32 * wn + 16 * ni + rl;
            float bv = bvec[n];
#pragma unroll
            for (int mi = 0; mi < 4; ++mi) {
                int rb = mtile * 128 + 64 * wm + 16 * mi + (lane >> 4) * 4;
#pragma unroll
                for (int v = 0; v < 4; ++v)
                    G1[(size_t)(rb + v) * 1024 + n] = f2bf(acc[mi][ni][v] + bv);
            }
        }
    } else {                                // ============== bwd 64x128 tile
        __shared__ int evs[64];
        int ntile = bid - 128;              // 0..7 (bwd cols 0..1023)
        int n0 = ntile * 128;
        if (tid < 64)
            evs[tid] = (int)X[((size_t)tid * S_ + (S_ - 1)) * 8];
        __syncthreads();

        // per-lane gathered A-frag base: lane l, sub-tile mi reads row
        // R = evs[16*mi + (l&15)] from the Aemb fragment table.
        int cbase[4];
#pragma unroll
        for (int mi = 0; mi < 4; ++mi) {
            int R = evs[16 * mi + rl];
            int g = R >> 4;
            cbase[mi] = (g >> 3) * 32768 + (g & 7) * 512 + (lane >> 4) * 128 + (R & 15) * 8;
        }
        // B: fragment group g = 64 + ntile*8 + 2*wave + ni
        const unsigned short* pb = WT + ((size_t)(8 + ntile) * 64 + 2 * wave) * 512 + lane * 8;

        floatx4 acc[4][2];
#pragma unroll
        for (int mi = 0; mi < 4; ++mi)
#pragma unroll
            for (int ni = 0; ni < 2; ++ni) acc[mi][ni] = (floatx4){0.f, 0.f, 0.f, 0.f};

#pragma unroll
        for (int kt = 0; kt < 8; ++kt) {
            bf16x8 afc[4], bfc[2];
#pragma unroll
            for (int mi = 0; mi < 4; ++mi)
                afc[mi] = *(const bf16x8*)(Aemb + (size_t)cbase[mi] + (size_t)kt * 4096);
#pragma unroll
            for (int ni = 0; ni < 2; ++ni)
                bfc[ni] = *(const bf16x8*)(pb + (size_t)kt * 4096 + ni * 512);
#pragma unroll
            for (int mi = 0; mi < 4; ++mi)
#pragma unroll
                for (int ni = 0; ni < 2; ++ni)
                    acc[mi][ni] = __builtin_amdgcn_mfma_f32_16x16x32_bf16(afc[mi], bfc[ni], acc[mi][ni], 0, 0, 0);
        }

#pragma unroll
        for (int ni = 0; ni < 2; ++ni) {
            int n = n0 + 32 * wave + 16 * ni + rl;
            float bv = bvec[1024 + n];
#pragma unroll
            for (int mi = 0; mi < 4; ++mi) {
                int rb = 16 * mi + (lane >> 4) * 4;     // batch row
#pragma unroll
                for (int v = 0; v < 4; ++v)
                    Gb[(size_t)(rb + v) * 1024 + n] = f2bf(acc[mi][ni][v] + bv);
            }
        }
    }
}

// ---------------- K3: gather-scan (full register preload) + fused final -----
__global__ __launch_bounds__(512, 4) void scanF(
    const float* __restrict__ X, const unsigned short* __restrict__ G1,
    const unsigned short* __restrict__ Gb, const float* __restrict__ W4,
    const float* __restrict__ Wn, const float* __restrict__ Wo,
    const float* __restrict__ bo, float* __restrict__ PQ,
    unsigned* __restrict__ bcnt, float* __restrict__ out) {
    __shared__ float LX[512];               // 64 steps x 8 floats
    __shared__ float LN[64][4];             // per-token n4 = num @ Wn
    __shared__ int   LO[64];                // per-token G1 row byte-offset
    __shared__ unsigned lastf;
    __shared__ float red[8];
    int bid = blockIdx.x;
    int b = bid >> 3, chunk = bid & 7;
    int s0 = chunk * 64;
    int j = threadIdx.x;                    // chain 0..511

    // hoisted: w4p loads are independent of LX (in flight across the barrier)
    float2 w4p[NOUT_];
#pragma unroll
    for (int q = 0; q < NOUT_; ++q)
        w4p[q] = *(const float2*)(W4 + (size_t)q * NG_ + 2 * j);

    if (j < 128) {
        const float* xb = X + ((size_t)b * S_ + s0) * 8;
        *(float4*)&LX[4 * j] = *(const float4*)(xb + 4 * j);
    }
    __syncthreads();

    if (j < 64) LO[j] = (int)LX[j * 8] * 2048;   // G1 row = 1024 shorts = 2KB
    if (j < 256) {                          // token t = j>>2, output q = j&3
        int t = j >> 2, q = j & 3;
        float s = 0.f;
#pragma unroll
        for (int i = 0; i < NIN_; ++i) s = fmaf(LX[t * 8 + 1 + i], Wn[i * NOUT_ + q], s);
        LN[t][q] = s;
    }
    __syncthreads();

    // ---- full preload: 64 independent 4B gathers, one burst, one drain ----
    const char* Gbase = (const char*)G1 + 4 * j;
    unsigned gp[64];
#pragma unroll
    for (int m = 0; m < 16; ++m) {
        int4 lo = *(const int4*)&LO[4 * m];
        gp[4 * m + 0] = *(const unsigned*)(Gbase + lo.x);
        gp[4 * m + 1] = *(const unsigned*)(Gbase + lo.y);
        gp[4 * m + 2] = *(const unsigned*)(Gbase + lo.z);
        gp[4 * m + 3] = *(const unsigned*)(Gbase + lo.w);
    }

    float P = 1.f, Q = 0.f;
#pragma unroll
    for (int s = 0; s < 64; ++s) {
        unsigned gpc = gp[s];               // static index (full unroll)
        float gz = bf2f((unsigned short)(gpc & 0xffffu));
        float gf = bf2f((unsigned short)(gpc >> 16));
        float4 n4 = *(const float4*)(&LN[s][0]);    // uniform b128 broadcast
        gz = fmaf(n4.x, w4p[0].x, gz);
        gz = fmaf(n4.y, w4p[1].x, gz);
        gz = fmaf(n4.z, w4p[2].x, gz);
        gz = fmaf(n4.w, w4p[3].x, gz);
        gf = fmaf(n4.x, w4p[0].y, gf);
        gf = fmaf(n4.y, w4p[1].y, gf);
        gf = fmaf(n4.z, w4p[2].y, gf);
        gf = fmaf(n4.w, w4p[3].y, gf);
        float z = tanhf_(gz);
        float f = sigmoidf_(gf);
        Q = fmaf(f, Q - z, z);              // f*Q + (1-f)*z
        P *= f;
    }
    {   // write-through 8B store to the coherent point (R3-proven)
        union { float2 f; ull q; } pv;
        pv.f = make_float2(P, Q);
        __hip_atomic_store((ull*)PQ + (size_t)bid * 512 + j, pv.q,
                           __ATOMIC_RELAXED, __HIP_MEMORY_SCOPE_AGENT);
    }

    // -------- per-batch trigger: 8th-arriving chunk block runs the fold -----
    __syncthreads();                        // drains the PQ stores (vmcnt0)
    if (j == 0) {
        unsigned old = __hip_atomic_fetch_add(bcnt + b, 1u, __ATOMIC_RELAXED,
                                              __HIP_MEMORY_SCOPE_AGENT);
        lastf = (old == 7u);
    }
    __syncthreads();

    if (lastf) {                            // ---- final fold for batch b ----
        float h = 0.f;
#pragma unroll
        for (int c = 0; c < 8; ++c) {
            union { float2 f; ull q; } pv;
            pv.q = __hip_atomic_load((const ull*)PQ + ((size_t)b * 8 + c) * 512 + j,
                                     __ATOMIC_RELAXED, __HIP_MEMORY_SCOPE_AGENT);
            h = fmaf(pv.f.x, h, pv.f.y);
        }

        const float* xr = X + ((size_t)b * S_ + (S_ - 1)) * 8;
        float n4[NOUT_];
#pragma unroll
        for (int q = 0; q < NOUT_; ++q) {
            float s = 0.f;
#pragma unroll
            for (int i = 0; i < NIN_; ++i) s = fmaf(xr[1 + i], Wn[i * NOUT_ + q], s);
            n4[q] = s;
        }
        unsigned gpc = *(const unsigned*)(Gb + (size_t)b * 1024 + 2 * j);  // coalesced
        float gz = bf2f((unsigned short)(gpc & 0xffffu));
        float gf = bf2f((unsigned short)(gpc >> 16));
#pragma unroll
        for (int q = 0; q < NOUT_; ++q) {
            float2 w = *(const float2*)(W4 + (size_t)q * NG_ + 1024 + 2 * j);
            gz = fmaf(n4[q], w.x, gz);
            gf = fmaf(n4[q], w.y, gf);
        }
        float hb = (1.f - sigmoidf_(gf)) * tanhf_(gz);

        float partial = fmaf(h, Wo[j], hb * Wo[512 + j]);
#pragma unroll
        for (int off = 32; off > 0; off >>= 1)
            partial += __shfl_down(partial, off);
        if ((j & 63) == 0) red[j >> 6] = partial;
        __syncthreads();
        if (j == 0) {
            float s = bo[0];
#pragma unroll
            for (int w = 0; w < 8; ++w) s += red[w];
            out[b] = s;
        }
    }
}

extern "C" void kernel_launch(void* const* d_in, const int* in_sizes, int n_in,
                              void* d_out, int out_size, void* d_ws, size_t ws_size,
                              hipStream_t stream) {
    const float* X   = (const float*)d_in[0];
    const float* emb = (const float*)d_in[1];
    const float* Wn  = (const float*)d_in[2];
    const float* bn  = (const float*)d_in[3];
    const float* Wf  = (const float*)d_in[4];
    const float* bfv = (const float*)d_in[5];
    const float* Wb  = (const float*)d_in[6];
    const float* bb  = (const float*)d_in[7];
    const float* Wo  = (const float*)d_in[8];
    const float* bo  = (const float*)d_in[9];
    float* out = (float*)d_out;

    size_t off_A  = 0;
    size_t off_WT = off_A  + (size_t)VP_ * EMB_ * 2;          // 512 KB
    size_t off_G1 = off_WT + (size_t)NG_ * EMB_ * 2;          // +1 MB
    size_t off_Gb = off_G1 + (size_t)VP_ * 1024 * 2;          // +2 MB
    size_t off_W4 = off_Gb + (size_t)B_ * 1024 * 2;           // +128 KB
    size_t off_bv = off_W4 + (size_t)NOUT_ * NG_ * 4;         // +32 KB
    size_t off_PQ = off_bv + (size_t)NG_ * 4;                 // +8 KB
    size_t off_bc = off_PQ + (size_t)B_ * 8 * 512 * 2 * sizeof(float);  // +2 MB
    size_t need   = off_bc + 64 * sizeof(unsigned);
    if (ws_size < need) return;

    unsigned short* Aemb = (unsigned short*)((char*)d_ws + off_A);
    unsigned short* WT   = (unsigned short*)((char*)d_ws + off_WT);
    unsigned short* G1   = (unsigned short*)((char*)d_ws + off_G1);
    unsigned short* Gb   = (unsigned short*)((char*)d_ws + off_Gb);
    float*          W4   = (float*)((char*)d_ws + off_W4);
    float*          bvec = (float*)((char*)d_ws + off_bv);
    float*          PQ   = (float*)((char*)d_ws + off_PQ);
    unsigned*       bcnt = (unsigned*)((char*)d_ws + off_bc);

    prep<<<200, 256, 0, stream>>>(emb, bn, Wf, bfv, Wb, bb, Aemb, WT, W4, bvec, bcnt);
    gemmG<<<136, 256, 0, stream>>>(X, Aemb, WT, bvec, G1, Gb);
    scanF<<<512, 512, 0, stream>>>(X, G1, Gb, W4, Wn, Wo, bo, PQ, bcnt, out);
}